// Round 3
// baseline (1181.835 us; speedup 1.0000x reference)
//
#include <hip/hip_runtime.h>
#include <hip/hip_bf16.h>
#include <math.h>

typedef unsigned short ushort_t;
typedef __bf16 bf16x8 __attribute__((ext_vector_type(8)));
typedef float f32x4 __attribute__((ext_vector_type(4)));

#define BB 128
#define TT 24
#define EE 512
#define VV 30000
#define HH 1024
#define GG 4096
#define MM (BB*TT)   // 3072 rows, m = t*128 + b

static __device__ __forceinline__ ushort_t f2bf(float x) {
  __hip_bfloat16 h = __float2bfloat16(x);
  return __builtin_bit_cast(ushort_t, h);
}

// async global->LDS, 16B per lane; lds base must be wave-uniform
static __device__ __forceinline__ void gld_lds16(const void* g, void* l) {
  __builtin_amdgcn_global_load_lds((const __attribute__((address_space(1))) void*)g,
                                   (__attribute__((address_space(3))) void*)l, 16, 0, 0);
}

// ---------------- prep kernels ----------------

__global__ void cast_bf16_k(const float* __restrict__ s, ushort_t* __restrict__ d, int n4) {
  int i = blockIdx.x * blockDim.x + threadIdx.x;
  int stride = gridDim.x * blockDim.x;
  for (; i < n4; i += stride) {
    float4 v = reinterpret_cast<const float4*>(s)[i];
    ushort4 o;
    o.x = f2bf(v.x); o.y = f2bf(v.y); o.z = f2bf(v.z); o.w = f2bf(v.w);
    reinterpret_cast<ushort4*>(d)[i] = o;
  }
}

__global__ void bias_sum_k(const float* __restrict__ bi, const float* __restrict__ bh,
                           float* __restrict__ bs) {
  int i = blockIdx.x * blockDim.x + threadIdx.x;
  if (i < GG) bs[i] = bi[i] + bh[i];
}

__global__ void build_xa_k(const float* __restrict__ emb, const int* __restrict__ captions,
                           const int* __restrict__ pad_idx, const float* __restrict__ features,
                           ushort_t* __restrict__ xa) {
  int row = blockIdx.x;          // 0..3071, row = t*128+b
  int t = row >> 7;
  int b = row & 127;
  int cap = (t == 0) ? pad_idx[0] : captions[b * TT + (t - 1)];
  const float* s0 = emb + (size_t)cap * EE;
  const float* s1 = features + (size_t)b * EE;
  ushort_t* d = xa + (size_t)row * (2 * EE);
  for (int e = threadIdx.x; e < EE; e += 256) {
    d[e] = f2bf(s0[e]);
    d[EE + e] = f2bf(s1[e]);
  }
}

__global__ void zero_bar_k(int* __restrict__ bar) {
  if (threadIdx.x < 2) bar[threadIdx.x] = 0;
}

// ---------------- GEMM, m97 structure ----------------
// A,B: [rows][K=1024] bf16. out[m][n] = dot(A[m],B[n]).
// MODE 0 (xg): m-tile == one t (m0 = t*128); writes xgT[t][n][b] = [t*4096+n]*128 + b, + bias[n]
// MODE 1 (logits): m=v (guard<M), n=b*24+t -> out[b*V*T + v*T + t] + bias[v]
template<int MODE>
__global__ __launch_bounds__(256) void gemm_bt(
    const ushort_t* __restrict__ A,
    const ushort_t* __restrict__ Bm,
    const float* __restrict__ bias,
    float* __restrict__ out,
    int M, int N, int nx, int cpx)
{
  constexpr int K = 1024;
  __shared__ __align__(16) ushort_t As[128 * 64];
  __shared__ __align__(16) ushort_t Bs[128 * 64];
  int bid = blockIdx.x;
  int bid_s = (bid & 7) * cpx + (bid >> 3);       // XCD-contiguous chunks
  const int n0 = (bid_s % nx) * 128;
  const int m0 = (bid_s / nx) * 128;
  const int tid = threadIdx.x;
  const int wid = tid >> 6, lane = tid & 63;
  const int wm = (wid >> 1) * 64, wn = (wid & 1) * 64;
  const int srow = lane >> 3;            // 0..7
  const int scol = (lane & 7) * 8;       // element offset
  const int rr = lane & 15, kb = (lane >> 4) * 8;
  f32x4 acc[4][4] = {};
  for (int k0 = 0; k0 < K; k0 += 64) {
    #pragma unroll
    for (int p = 0; p < 4; ++p) {
      int c = p * 4 + wid;               // chunk 0..15, 8 rows each
      int row = c * 8 + srow;
      gld_lds16(A + (size_t)(m0 + row) * K + k0 + scol, As + c * 512);
      gld_lds16(Bm + (size_t)(n0 + row) * K + k0 + scol, Bs + c * 512);
    }
    __syncthreads();
    #pragma unroll
    for (int kk = 0; kk < 2; ++kk) {
      const int kof = kk * 32 + kb;
      bf16x8 af[4], bfv[4];
      #pragma unroll
      for (int i = 0; i < 4; ++i)
        af[i] = *reinterpret_cast<const bf16x8*>(As + (wm + i * 16 + rr) * 64 + kof);
      #pragma unroll
      for (int j = 0; j < 4; ++j)
        bfv[j] = *reinterpret_cast<const bf16x8*>(Bs + (wn + j * 16 + rr) * 64 + kof);
      #pragma unroll
      for (int i = 0; i < 4; ++i)
        #pragma unroll
        for (int j = 0; j < 4; ++j)
          acc[i][j] = __builtin_amdgcn_mfma_f32_16x16x32_bf16(af[i], bfv[j], acc[i][j], 0, 0, 0);
    }
    __syncthreads();
  }
  const int l16 = lane & 15, l4 = lane >> 4;
  if (MODE == 0) {
    const int t_blk = m0 >> 7;
    #pragma unroll
    for (int i = 0; i < 4; ++i) {
      #pragma unroll
      for (int j = 0; j < 4; ++j) {
        int n = n0 + wn + j * 16 + l16;
        float bv = bias[n];
        #pragma unroll
        for (int r = 0; r < 4; ++r) {
          int b = wm + i * 16 + l4 * 4 + r;     // m - m0
          out[((size_t)t_blk * GG + n) * BB + b] = acc[i][j][r] + bv;
        }
      }
    }
  } else {
    #pragma unroll
    for (int i = 0; i < 4; ++i) {
      #pragma unroll
      for (int r = 0; r < 4; ++r) {
        int v = m0 + wm + i * 16 + l4 * 4 + r;
        if (v < M) {
          float bv = bias[v];
          #pragma unroll
          for (int j = 0; j < 4; ++j) {
            int n = n0 + wn + j * 16 + l16;
            int bb = n / TT, tq = n - bb * TT;
            out[(size_t)bb * ((size_t)VV * TT) + (size_t)v * TT + tq] = acc[i][j][r] + bv;
          }
        }
      }
    }
  }
}

// ---------------- fused persistent LSTM (all 24 steps, grid barrier) ----------------
// 256 blocks x 512 threads. Block: jblk = bid&63 -> 16 j-cols x 4 gates; mblk = bid>>6 -> 32 batch.
// Wave w: ks = w>>1 (K quarter), msub = (w&1)*16. No LDS operand staging; frags direct from global.
// h history lives in hs[b*24+t]; c in registers of the ks==0 waves.
__global__ __launch_bounds__(512, 1) void lstm_seq_k(
    const ushort_t* __restrict__ Whh,    // [4096][1024] bf16
    const float* __restrict__ xgT,       // [24][4096][128] f32, bias included
    ushort_t* __restrict__ hs,           // [3072][1024] bf16, row = b*24+t
    int* __restrict__ bar)               // bar[0]=cnt, bar[1]=release
{
  __shared__ f32x4 red[6][64][4];        // 24 KB: [slot][lane][gate]
  const int tid = threadIdx.x, wid = tid >> 6, lane = tid & 63;
  const int l16 = lane & 15, l4 = lane >> 4;
  const int jblk = blockIdx.x & 63, mblk = blockIdx.x >> 6;
  const int j0 = jblk * 16, m0 = mblk * 32;
  const int ks = wid >> 1;               // 0..3
  const int msub = (wid & 1) * 16;
  // B fragment bases (4 gates), fixed across t: Whh[g*1024 + j0 + l16][ks*256 + l4*8]
  const ushort_t* Bb[4];
  #pragma unroll
  for (int g = 0; g < 4; ++g)
    Bb[g] = Whh + ((size_t)(g * 1024 + j0 + l16) << 10) + ks * 256 + l4 * 8;
  // A fragment row (batch index) for this lane
  const int arow = m0 + msub + l16;
  float c_reg[4] = {0.f, 0.f, 0.f, 0.f};
  for (int t = 0; t < TT; ++t) {
    f32x4 acc[4] = {{0.f, 0.f, 0.f, 0.f}, {0.f, 0.f, 0.f, 0.f},
                    {0.f, 0.f, 0.f, 0.f}, {0.f, 0.f, 0.f, 0.f}};
    f32x4 xv[4];
    if (ks == 0) {
      const float* xp = xgT + ((size_t)(t * GG + j0 + l16)) * BB + m0 + msub + l4 * 4;
      #pragma unroll
      for (int g = 0; g < 4; ++g)
        xv[g] = *reinterpret_cast<const f32x4*>(xp + (size_t)g * 1024 * BB);
    }
    if (t > 0) {
      const ushort_t* Ab = hs + (((size_t)arow * TT + (t - 1)) << 10) + ks * 256 + l4 * 8;
      #pragma unroll
      for (int kc = 0; kc < 8; ++kc) {
        bf16x8 af = *reinterpret_cast<const bf16x8*>(Ab + kc * 32);
        #pragma unroll
        for (int g = 0; g < 4; ++g) {
          bf16x8 bv = *reinterpret_cast<const bf16x8*>(Bb[g] + kc * 32);
          acc[g] = __builtin_amdgcn_mfma_f32_16x16x32_bf16(af, bv, acc[g], 0, 0, 0);
        }
      }
    }
    if (ks != 0) {
      int slot = (ks - 1) * 2 + (wid & 1);
      #pragma unroll
      for (int g = 0; g < 4; ++g) red[slot][lane][g] = acc[g];
    }
    __syncthreads();
    if (ks == 0) {
      #pragma unroll
      for (int s = 0; s < 3; ++s)
        #pragma unroll
        for (int g = 0; g < 4; ++g)
          acc[g] += red[s * 2 + (wid & 1)][lane][g];
      #pragma unroll
      for (int r = 0; r < 4; ++r) {
        int b = m0 + msub + l4 * 4 + r;
        float gi = acc[0][r] + xv[0][r];
        float gf = acc[1][r] + xv[1][r];
        float gg = acc[2][r] + xv[2][r];
        float go = acc[3][r] + xv[3][r];
        gi = 1.f / (1.f + expf(-gi));
        gf = 1.f / (1.f + expf(-gf));
        go = 1.f / (1.f + expf(-go));
        float cn = gf * c_reg[r] + gi * tanhf(gg);
        c_reg[r] = cn;
        float hn = go * tanhf(cn);
        hs[(((size_t)b * TT + t) << 10) + j0 + l16] = f2bf(hn);
      }
    }
    // grid barrier between steps (generation-based, monotone counter)
    if (t < TT - 1) {
      __syncthreads();
      if (tid == 0) {
        __threadfence();
        int a = atomicAdd(bar, 1) + 1;
        if (a == 256 * (t + 1)) {
          __hip_atomic_store(bar + 1, t + 1, __ATOMIC_RELEASE, __HIP_MEMORY_SCOPE_AGENT);
        } else {
          while (__hip_atomic_load(bar + 1, __ATOMIC_ACQUIRE, __HIP_MEMORY_SCOPE_AGENT) < t + 1)
            __builtin_amdgcn_s_sleep(1);
        }
        __threadfence();
      }
      __syncthreads();
    }
  }
}

// ---------------- launcher ----------------

extern "C" void kernel_launch(void* const* d_in, const int* in_sizes, int n_in,
                              void* d_out, int out_size, void* d_ws, size_t ws_size,
                              hipStream_t stream) {
  const float* features = (const float*)d_in[0];
  const int*   captions = (const int*)d_in[1];
  const int*   pad_idx  = (const int*)d_in[2];
  const float* emb      = (const float*)d_in[3];
  const float* W_ih     = (const float*)d_in[4];
  const float* W_hh     = (const float*)d_in[5];
  const float* b_ih     = (const float*)d_in[6];
  const float* b_hh     = (const float*)d_in[7];
  const float* W_out    = (const float*)d_in[8];
  const float* b_out    = (const float*)d_in[9];
  float* out = (float*)d_out;

  char* w = (char*)d_ws;
  auto carve = [&](size_t bytes) {
    char* p = w;
    w += (bytes + 255) & ~(size_t)255;
    return p;
  };
  ushort_t* Wih_b  = (ushort_t*)carve((size_t)GG * HH * 2);
  ushort_t* Whh_b  = (ushort_t*)carve((size_t)GG * HH * 2);
  ushort_t* Wout_b = (ushort_t*)carve((size_t)30080 * HH * 2);  // padded to tile multiple
  ushort_t* xa     = (ushort_t*)carve((size_t)MM * HH * 2);
  float*    xgT    = (float*)carve((size_t)MM * GG * 4);        // [24][4096][128]
  ushort_t* hs     = (ushort_t*)carve((size_t)MM * HH * 2);
  float*    bsum   = (float*)carve((size_t)GG * 4);
  int*      bar    = (int*)carve(256);

  cast_bf16_k<<<dim3(1024), 256, 0, stream>>>(W_ih, Wih_b, GG * HH / 4);
  cast_bf16_k<<<dim3(1024), 256, 0, stream>>>(W_hh, Whh_b, GG * HH / 4);
  cast_bf16_k<<<dim3(2048), 256, 0, stream>>>(W_out, Wout_b, VV * HH / 4);
  bias_sum_k<<<dim3(16), 256, 0, stream>>>(b_ih, b_hh, bsum);
  build_xa_k<<<dim3(MM), 256, 0, stream>>>(emb, captions, pad_idx, features, xa);
  zero_bar_k<<<dim3(1), 64, 0, stream>>>(bar);

  // xgT[t][n][b] = (xa @ W_ih^T + b)  ; grid 32x24=768 = 8*96
  gemm_bt<0><<<dim3(768), 256, 0, stream>>>(xa, Wih_b, bsum, xgT, MM, GG, 32, 96);

  // all 24 LSTM steps in one persistent kernel (h history in hs)
  lstm_seq_k<<<dim3(256), 512, 0, stream>>>(Whh_b, xgT, hs, bar);

  // out[b][v][t] = dot(hs[b*24+t], W_out[v]) + b_out[v]; grid 24x235=5640 = 8*705
  gemm_bt<1><<<dim3(5640), 256, 0, stream>>>(Wout_b, hs, b_out, out, VV, MM, 24, 705);
}

// Round 4
// 674.810 us; speedup vs baseline: 1.7514x; 1.7514x over previous
//
#include <hip/hip_runtime.h>
#include <hip/hip_bf16.h>
#include <math.h>

typedef unsigned short ushort_t;
typedef unsigned long long u64;
typedef __bf16 bf16x8 __attribute__((ext_vector_type(8)));
typedef float f32x4 __attribute__((ext_vector_type(4)));

#define BB 128
#define TT 24
#define EE 512
#define VV 30000
#define HH 1024
#define GG 4096
#define MM (BB*TT)   // 3072 rows, m = t*128 + b

static __device__ __forceinline__ ushort_t f2bf(float x) {
  __hip_bfloat16 h = __float2bfloat16(x);
  return __builtin_bit_cast(ushort_t, h);
}

// async global->LDS, 16B per lane; lds base must be wave-uniform
static __device__ __forceinline__ void gld_lds16(const void* g, void* l) {
  __builtin_amdgcn_global_load_lds((const __attribute__((address_space(1))) void*)g,
                                   (__attribute__((address_space(3))) void*)l, 16, 0, 0);
}

// ---------------- prep kernels ----------------

__global__ void cast_bf16_k(const float* __restrict__ s, ushort_t* __restrict__ d, int n4) {
  int i = blockIdx.x * blockDim.x + threadIdx.x;
  int stride = gridDim.x * blockDim.x;
  for (; i < n4; i += stride) {
    float4 v = reinterpret_cast<const float4*>(s)[i];
    ushort4 o;
    o.x = f2bf(v.x); o.y = f2bf(v.y); o.z = f2bf(v.z); o.w = f2bf(v.w);
    reinterpret_cast<ushort4*>(d)[i] = o;
  }
}

__global__ void bias_sum_k(const float* __restrict__ bi, const float* __restrict__ bh,
                           float* __restrict__ bs) {
  int i = blockIdx.x * blockDim.x + threadIdx.x;
  if (i < GG) bs[i] = bi[i] + bh[i];
}

__global__ void build_xa_k(const float* __restrict__ emb, const int* __restrict__ captions,
                           const int* __restrict__ pad_idx, const float* __restrict__ features,
                           ushort_t* __restrict__ xa) {
  int row = blockIdx.x;          // 0..3071, row = t*128+b
  int t = row >> 7;
  int b = row & 127;
  int cap = (t == 0) ? pad_idx[0] : captions[b * TT + (t - 1)];
  const float* s0 = emb + (size_t)cap * EE;
  const float* s1 = features + (size_t)b * EE;
  ushort_t* d = xa + (size_t)row * (2 * EE);
  for (int e = threadIdx.x; e < EE; e += 256) {
    d[e] = f2bf(s0[e]);
    d[EE + e] = f2bf(s1[e]);
  }
}

// zero the 256 arrival flags + 8 release copies (stride 64), sc1 so MALL is fresh
__global__ void zero_bar_k(int* __restrict__ bar) {
  for (int i = threadIdx.x; i < 768; i += 256)
    __hip_atomic_store(&bar[i], 0, __ATOMIC_RELAXED, __HIP_MEMORY_SCOPE_AGENT);
}

// ---------------- GEMM, m97 structure ----------------
// A,B: [rows][K=1024] bf16. out[m][n] = dot(A[m],B[n]).
// MODE 0 (xg): m-tile == one t (m0 = t*128); writes xgT[t][n][b] = [t*4096+n]*128 + b, + bias[n]
// MODE 1 (logits): m=v (guard<M), n=b*24+t -> out[b*V*T + v*T + t] + bias[v]
template<int MODE>
__global__ __launch_bounds__(256) void gemm_bt(
    const ushort_t* __restrict__ A,
    const ushort_t* __restrict__ Bm,
    const float* __restrict__ bias,
    float* __restrict__ out,
    int M, int N, int nx, int cpx)
{
  constexpr int K = 1024;
  __shared__ __align__(16) ushort_t As[128 * 64];
  __shared__ __align__(16) ushort_t Bs[128 * 64];
  int bid = blockIdx.x;
  int bid_s = (bid & 7) * cpx + (bid >> 3);       // XCD-contiguous chunks
  const int n0 = (bid_s % nx) * 128;
  const int m0 = (bid_s / nx) * 128;
  const int tid = threadIdx.x;
  const int wid = tid >> 6, lane = tid & 63;
  const int wm = (wid >> 1) * 64, wn = (wid & 1) * 64;
  const int srow = lane >> 3;            // 0..7
  const int scol = (lane & 7) * 8;       // element offset
  const int rr = lane & 15, kb = (lane >> 4) * 8;
  f32x4 acc[4][4] = {};
  for (int k0 = 0; k0 < K; k0 += 64) {
    #pragma unroll
    for (int p = 0; p < 4; ++p) {
      int c = p * 4 + wid;               // chunk 0..15, 8 rows each
      int row = c * 8 + srow;
      gld_lds16(A + (size_t)(m0 + row) * K + k0 + scol, As + c * 512);
      gld_lds16(Bm + (size_t)(n0 + row) * K + k0 + scol, Bs + c * 512);
    }
    __syncthreads();
    #pragma unroll
    for (int kk = 0; kk < 2; ++kk) {
      const int kof = kk * 32 + kb;
      bf16x8 af[4], bfv[4];
      #pragma unroll
      for (int i = 0; i < 4; ++i)
        af[i] = *reinterpret_cast<const bf16x8*>(As + (wm + i * 16 + rr) * 64 + kof);
      #pragma unroll
      for (int j = 0; j < 4; ++j)
        bfv[j] = *reinterpret_cast<const bf16x8*>(Bs + (wn + j * 16 + rr) * 64 + kof);
      #pragma unroll
      for (int i = 0; i < 4; ++i)
        #pragma unroll
        for (int j = 0; j < 4; ++j)
          acc[i][j] = __builtin_amdgcn_mfma_f32_16x16x32_bf16(af[i], bfv[j], acc[i][j], 0, 0, 0);
    }
    __syncthreads();
  }
  const int l16 = lane & 15, l4 = lane >> 4;
  if (MODE == 0) {
    const int t_blk = m0 >> 7;
    #pragma unroll
    for (int i = 0; i < 4; ++i) {
      #pragma unroll
      for (int j = 0; j < 4; ++j) {
        int n = n0 + wn + j * 16 + l16;
        float bv = bias[n];
        #pragma unroll
        for (int r = 0; r < 4; ++r) {
          int b = wm + i * 16 + l4 * 4 + r;     // m - m0
          out[((size_t)t_blk * GG + n) * BB + b] = acc[i][j][r] + bv;
        }
      }
    }
  } else {
    #pragma unroll
    for (int i = 0; i < 4; ++i) {
      #pragma unroll
      for (int r = 0; r < 4; ++r) {
        int v = m0 + wm + i * 16 + l4 * 4 + r;
        if (v < M) {
          float bv = bias[v];
          #pragma unroll
          for (int j = 0; j < 4; ++j) {
            int n = n0 + wn + j * 16 + l16;
            int bb = n / TT, tq = n - bb * TT;
            out[(size_t)bb * ((size_t)VV * TT) + (size_t)v * TT + tq] = acc[i][j][r] + bv;
          }
        }
      }
    }
  }
}

// ---------------- fused persistent LSTM (all 24 steps, flag barrier) ----------------
// 256 blocks x 512 threads, 1 block/CU. Block: jblk = bid&63 (16 j x 4 gates),
// mblk = bid>>6 (32 batch). Wave w: ks = w>>1 (K quarter), msub = (w&1)*16.
// W_hh fragments live in REGISTERS (loop-invariant). h state (hs) is read/written with
// relaxed agent-scope (sc1) atomics -> MALL-coherent, NO cache-wide fences needed.
__global__ __launch_bounds__(512, 1) void lstm_seq_k(
    const ushort_t* __restrict__ Whh,    // [4096][1024] bf16
    const float* __restrict__ xgT,       // [24][4096][128] f32, bias included
    ushort_t* __restrict__ hs,           // [3072][1024] bf16, row = b*24+t
    int* __restrict__ bar)               // [0..255] arrival flags; [256+c*64] release copies
{
  __shared__ f32x4 red[6][64][4];        // 24 KB
  const int tid = threadIdx.x, wid = tid >> 6, lane = tid & 63;
  const int l16 = lane & 15, l4 = lane >> 4;
  const int bid = blockIdx.x;
  const int jblk = bid & 63, mblk = bid >> 6;
  const int j0 = jblk * 16, m0 = mblk * 32;
  const int ks = wid >> 1;               // 0..3 (K quarter)
  const int msub = (wid & 1) * 16;
  int* flags = bar;
  int* rel = bar + 256;

  // hoist W_hh fragments into registers: 4 gates x 8 kc x bf16x8 = 128 VGPRs
  bf16x8 Breg[4][8];
  #pragma unroll
  for (int g = 0; g < 4; ++g) {
    const ushort_t* bp = Whh + ((size_t)(g * 1024 + j0 + l16) << 10) + ks * 256 + l4 * 8;
    #pragma unroll
    for (int kc = 0; kc < 8; ++kc)
      Breg[g][kc] = *reinterpret_cast<const bf16x8*>(bp + kc * 32);
  }
  const int arow = m0 + msub + l16;      // A-fragment batch row for this lane
  float c_reg[4] = {0.f, 0.f, 0.f, 0.f};

  for (int t = 0; t < TT; ++t) {
    f32x4 acc[4] = {};
    f32x4 xv[4];
    if (ks == 0) {
      const float* xp = xgT + ((size_t)(t * GG + j0 + l16)) * BB + m0 + msub + l4 * 4;
      #pragma unroll
      for (int g = 0; g < 4; ++g)
        xv[g] = *reinterpret_cast<const f32x4*>(xp + (size_t)g * 1024 * BB);
    }
    if (t > 0) {
      // h from hs[arow][t-1], sc1 loads (bypass L2, MALL-coherent)
      const u64* Ab = reinterpret_cast<const u64*>(
          hs + (((size_t)arow * TT + (t - 1)) << 10) + ks * 256 + l4 * 8);
      bf16x8 afs[8];
      #pragma unroll
      for (int kc = 0; kc < 8; ++kc) {
        union { u64 q[2]; bf16x8 v; } u;
        u.q[0] = __hip_atomic_load(Ab + kc * 8,     __ATOMIC_RELAXED, __HIP_MEMORY_SCOPE_AGENT);
        u.q[1] = __hip_atomic_load(Ab + kc * 8 + 1, __ATOMIC_RELAXED, __HIP_MEMORY_SCOPE_AGENT);
        afs[kc] = u.v;
      }
      #pragma unroll
      for (int kc = 0; kc < 8; ++kc)
        #pragma unroll
        for (int g = 0; g < 4; ++g)
          acc[g] = __builtin_amdgcn_mfma_f32_16x16x32_bf16(afs[kc], Breg[g][kc], acc[g], 0, 0, 0);
    }
    if (ks != 0) {
      int slot = (ks - 1) * 2 + (wid & 1);
      #pragma unroll
      for (int g = 0; g < 4; ++g) red[slot][lane][g] = acc[g];
    }
    __syncthreads();
    if (ks == 0) {
      #pragma unroll
      for (int s = 0; s < 3; ++s)
        #pragma unroll
        for (int g = 0; g < 4; ++g)
          acc[g] += red[s * 2 + (wid & 1)][lane][g];
      #pragma unroll
      for (int r = 0; r < 4; ++r) {
        int b = m0 + msub + l4 * 4 + r;
        float gi = acc[0][r] + xv[0][r];
        float gf = acc[1][r] + xv[1][r];
        float gg = acc[2][r] + xv[2][r];
        float go = acc[3][r] + xv[3][r];
        gi = 1.f / (1.f + expf(-gi));
        gf = 1.f / (1.f + expf(-gf));
        go = 1.f / (1.f + expf(-go));
        float cn = gf * c_reg[r] + gi * tanhf(gg);
        c_reg[r] = cn;
        float hn = go * tanhf(cn);
        // pack (j, j+1) into u32 across lane pair, store sc1 (write-through to MALL)
        unsigned hv = (unsigned)f2bf(hn);
        unsigned pv = (unsigned)__shfl_xor((int)hv, 1);
        if (!(l16 & 1)) {
          unsigned pk = (hv & 0xffffu) | (pv << 16);
          __hip_atomic_store(
              reinterpret_cast<unsigned*>(hs + (((size_t)b * TT + t) << 10) + j0 + l16),
              pk, __ATOMIC_RELAXED, __HIP_MEMORY_SCOPE_AGENT);
        }
      }
    }
    // flag-array grid barrier (no RMW, no cache-wide fences)
    if (t < TT - 1) {
      __syncthreads();   // per-wave vmcnt(0) drain precedes s_barrier -> hs stores at MALL
      if (bid == 0) {
        if (wid == 0) {
          if (lane == 0)
            __hip_atomic_store(&flags[0], t + 1, __ATOMIC_RELAXED, __HIP_MEMORY_SCOPE_AGENT);
          for (;;) {
            int a0 = __hip_atomic_load(&flags[lane],       __ATOMIC_RELAXED, __HIP_MEMORY_SCOPE_AGENT);
            int a1 = __hip_atomic_load(&flags[lane +  64], __ATOMIC_RELAXED, __HIP_MEMORY_SCOPE_AGENT);
            int a2 = __hip_atomic_load(&flags[lane + 128], __ATOMIC_RELAXED, __HIP_MEMORY_SCOPE_AGENT);
            int a3 = __hip_atomic_load(&flags[lane + 192], __ATOMIC_RELAXED, __HIP_MEMORY_SCOPE_AGENT);
            int mn = min(min(a0, a1), min(a2, a3));
            if (__all(mn >= t + 1)) break;
            __builtin_amdgcn_s_sleep(2);
          }
          if (lane < 8)
            __hip_atomic_store(&rel[lane * 64], t + 1, __ATOMIC_RELAXED, __HIP_MEMORY_SCOPE_AGENT);
        }
      } else {
        if (tid == 0) {
          __hip_atomic_store(&flags[bid], t + 1, __ATOMIC_RELAXED, __HIP_MEMORY_SCOPE_AGENT);
          while (__hip_atomic_load(&rel[(bid & 7) * 64], __ATOMIC_RELAXED, __HIP_MEMORY_SCOPE_AGENT) < t + 1)
            __builtin_amdgcn_s_sleep(4);
        }
      }
      __syncthreads();
    }
  }
}

// ---------------- launcher ----------------

extern "C" void kernel_launch(void* const* d_in, const int* in_sizes, int n_in,
                              void* d_out, int out_size, void* d_ws, size_t ws_size,
                              hipStream_t stream) {
  const float* features = (const float*)d_in[0];
  const int*   captions = (const int*)d_in[1];
  const int*   pad_idx  = (const int*)d_in[2];
  const float* emb      = (const float*)d_in[3];
  const float* W_ih     = (const float*)d_in[4];
  const float* W_hh     = (const float*)d_in[5];
  const float* b_ih     = (const float*)d_in[6];
  const float* b_hh     = (const float*)d_in[7];
  const float* W_out    = (const float*)d_in[8];
  const float* b_out    = (const float*)d_in[9];
  float* out = (float*)d_out;

  char* w = (char*)d_ws;
  auto carve = [&](size_t bytes) {
    char* p = w;
    w += (bytes + 255) & ~(size_t)255;
    return p;
  };
  ushort_t* Wih_b  = (ushort_t*)carve((size_t)GG * HH * 2);
  ushort_t* Whh_b  = (ushort_t*)carve((size_t)GG * HH * 2);
  ushort_t* Wout_b = (ushort_t*)carve((size_t)30080 * HH * 2);  // padded to tile multiple
  ushort_t* xa     = (ushort_t*)carve((size_t)MM * HH * 2);
  float*    xgT    = (float*)carve((size_t)MM * GG * 4);        // [24][4096][128]
  ushort_t* hs     = (ushort_t*)carve((size_t)MM * HH * 2);
  float*    bsum   = (float*)carve((size_t)GG * 4);
  int*      bar    = (int*)carve(4096);

  cast_bf16_k<<<dim3(1024), 256, 0, stream>>>(W_ih, Wih_b, GG * HH / 4);
  cast_bf16_k<<<dim3(1024), 256, 0, stream>>>(W_hh, Whh_b, GG * HH / 4);
  cast_bf16_k<<<dim3(2048), 256, 0, stream>>>(W_out, Wout_b, VV * HH / 4);
  bias_sum_k<<<dim3(16), 256, 0, stream>>>(b_ih, b_hh, bsum);
  build_xa_k<<<dim3(MM), 256, 0, stream>>>(emb, captions, pad_idx, features, xa);
  zero_bar_k<<<dim3(1), 256, 0, stream>>>(bar);

  // xgT[t][n][b] = (xa @ W_ih^T + b)  ; grid 32x24=768 = 8*96
  gemm_bt<0><<<dim3(768), 256, 0, stream>>>(xa, Wih_b, bsum, xgT, MM, GG, 32, 96);

  // all 24 LSTM steps in one persistent kernel (h history in hs)
  lstm_seq_k<<<dim3(256), 512, 0, stream>>>(Whh_b, xgT, hs, bar);

  // out[b][v][t] = dot(hs[b*24+t], W_out[v]) + b_out[v]; grid 24x235=5640 = 8*705
  gemm_bt<1><<<dim3(5640), 256, 0, stream>>>(Wout_b, hs, b_out, out, VV, MM, 24, 705);
}

// Round 5
// 618.468 us; speedup vs baseline: 1.9109x; 1.0911x over previous
//
#include <hip/hip_runtime.h>
#include <hip/hip_bf16.h>
#include <math.h>

typedef unsigned short ushort_t;
typedef unsigned long long u64;
typedef __bf16 bf16x8 __attribute__((ext_vector_type(8)));
typedef float f32x4 __attribute__((ext_vector_type(4)));

#define BB 128
#define TT 24
#define EE 512
#define VV 30000
#define HH 1024
#define GG 4096
#define MM (BB*TT)   // 3072 rows, m = t*128 + b

static __device__ __forceinline__ ushort_t f2bf(float x) {
  __hip_bfloat16 h = __float2bfloat16(x);
  return __builtin_bit_cast(ushort_t, h);
}

// async global->LDS, 16B per lane; lds base must be wave-uniform
static __device__ __forceinline__ void gld_lds16(const void* g, void* l) {
  __builtin_amdgcn_global_load_lds((const __attribute__((address_space(1))) void*)g,
                                   (__attribute__((address_space(3))) void*)l, 16, 0, 0);
}

// ---------------- prep kernels ----------------

__global__ void cast_bf16_k(const float* __restrict__ s, ushort_t* __restrict__ d, int n4) {
  int i = blockIdx.x * blockDim.x + threadIdx.x;
  int stride = gridDim.x * blockDim.x;
  for (; i < n4; i += stride) {
    float4 v = reinterpret_cast<const float4*>(s)[i];
    ushort4 o;
    o.x = f2bf(v.x); o.y = f2bf(v.y); o.z = f2bf(v.z); o.w = f2bf(v.w);
    reinterpret_cast<ushort4*>(d)[i] = o;
  }
}

__global__ void bias_sum_k(const float* __restrict__ bi, const float* __restrict__ bh,
                           float* __restrict__ bs) {
  int i = blockIdx.x * blockDim.x + threadIdx.x;
  if (i < GG) bs[i] = bi[i] + bh[i];
}

__global__ void build_xa_k(const float* __restrict__ emb, const int* __restrict__ captions,
                           const int* __restrict__ pad_idx, const float* __restrict__ features,
                           ushort_t* __restrict__ xa) {
  int row = blockIdx.x;          // 0..3071, row = t*128+b
  int t = row >> 7;
  int b = row & 127;
  int cap = (t == 0) ? pad_idx[0] : captions[b * TT + (t - 1)];
  const float* s0 = emb + (size_t)cap * EE;
  const float* s1 = features + (size_t)b * EE;
  ushort_t* d = xa + (size_t)row * (2 * EE);
  for (int e = threadIdx.x; e < EE; e += 256) {
    d[e] = f2bf(s0[e]);
    d[EE + e] = f2bf(s1[e]);
  }
}

// zero the 256 arrival flags + 8 release copies (stride 64)
__global__ void zero_bar_k(int* __restrict__ bar) {
  for (int i = threadIdx.x; i < 768; i += 256)
    __hip_atomic_store(&bar[i], 0, __ATOMIC_RELAXED, __HIP_MEMORY_SCOPE_AGENT);
}

// ---------------- GEMM: 128x128 tile, dbuf LDS, counted vmcnt, T2 swizzle ----------------
// A,B: [rows][K=1024] bf16. out[m][n] = dot(A[m],B[n]).
// XCD 2-D partition: xcd=(bid&7) -> (xm,xn); c=bid>>3 -> (c/swn, c%swn).
// MODE 0 (xg): writes xgT[t][n][b], t = m0>>7. MODE 1 (logits): out[b*V*T + v*T + t], guard v<M.
template<int MODE>
__global__ __launch_bounds__(256) void gemm_bt(
    const ushort_t* __restrict__ A,
    const ushort_t* __restrict__ Bm,
    const float* __restrict__ bias,
    float* __restrict__ out,
    int M, int N, int swn, int xn_cnt)
{
  constexpr int K = 1024;
  __shared__ __align__(16) ushort_t As[2][8192];
  __shared__ __align__(16) ushort_t Bs[2][8192];
  const int bid = blockIdx.x;
  const int xcd = bid & 7, c = bid >> 3;
  const int xn = xcd % xn_cnt, xm = xcd / xn_cnt;
  const int nblk = xn * swn + (c % swn);
  const int mblk = xm * (0) + 0;   // placeholder, computed below
  (void)mblk;
  const int mb = xm; // rows-of-XCDs index
  const int n0 = nblk * 128;
  const int m0 = (mb * ((gridDim.x >> 3) / swn) + (c / swn)) * 128;
  const int tid = threadIdx.x, wid = tid >> 6, lane = tid & 63;
  const int wm = (wid >> 1) * 64, wn_ = (wid & 1) * 64;
  const int srow = lane >> 3;                       // 0..7
  const int scolsw = ((lane & 7) ^ srow) * 8;       // inverse-swizzled source col (elements)
  const int rr = lane & 15, l4 = lane >> 4;
  const int swz = (rr & 7) << 4;                    // read-side byte swizzle
  const int col0 = (((l4 << 4) ^ swz) >> 1);        // kk=0 col (elements)
  const int col1 = (((64 | (l4 << 4)) ^ swz) >> 1); // kk=1 col (elements)

  f32x4 acc[4][4] = {};

  // stage K-tile (k0) into buffer buf: 8 gld_lds16 per thread (4 A + 4 B)
  auto stage = [&](int buf, int k0) {
    #pragma unroll
    for (int p = 0; p < 4; ++p) {
      int ch = p * 4 + wid;                // chunk 0..15, 8 rows each
      int row = ch * 8 + srow;
      gld_lds16(A + (size_t)(m0 + row) * K + k0 + scolsw, &As[buf][ch * 512]);
      gld_lds16(Bm + (size_t)(n0 + row) * K + k0 + scolsw, &Bs[buf][ch * 512]);
    }
  };

  stage(0, 0);
  int cur = 0;
  for (int tau = 0; tau < 16; ++tau) {
    if (tau < 15) {
      stage(cur ^ 1, (tau + 1) * 64);
      asm volatile("s_waitcnt vmcnt(8)" ::: "memory");   // tile tau landed; tau+1 in flight
    } else {
      asm volatile("s_waitcnt vmcnt(0)" ::: "memory");
    }
    __builtin_amdgcn_s_barrier();
    const ushort_t* Ac = As[cur];
    const ushort_t* Bc = Bs[cur];
    #pragma unroll
    for (int kk = 0; kk < 2; ++kk) {
      const int ce = kk ? col1 : col0;
      bf16x8 af[4], bfv[4];
      #pragma unroll
      for (int i = 0; i < 4; ++i)
        af[i] = *reinterpret_cast<const bf16x8*>(Ac + (wm + i * 16 + rr) * 64 + ce);
      #pragma unroll
      for (int j = 0; j < 4; ++j)
        bfv[j] = *reinterpret_cast<const bf16x8*>(Bc + (wn_ + j * 16 + rr) * 64 + ce);
      #pragma unroll
      for (int i = 0; i < 4; ++i)
        #pragma unroll
        for (int j = 0; j < 4; ++j)
          acc[i][j] = __builtin_amdgcn_mfma_f32_16x16x32_bf16(af[i], bfv[j], acc[i][j], 0, 0, 0);
    }
    asm volatile("" ::: "memory");
    __builtin_amdgcn_s_barrier();
    cur ^= 1;
  }

  const int l16 = lane & 15;
  if (MODE == 0) {
    const int t_blk = m0 >> 7;
    #pragma unroll
    for (int i = 0; i < 4; ++i) {
      #pragma unroll
      for (int j = 0; j < 4; ++j) {
        int n = n0 + wn_ + j * 16 + l16;
        float bv = bias[n];
        #pragma unroll
        for (int r = 0; r < 4; ++r) {
          int b = wm + i * 16 + l4 * 4 + r;     // m - m0
          out[((size_t)t_blk * GG + n) * BB + b] = acc[i][j][r] + bv;
        }
      }
    }
  } else {
    #pragma unroll
    for (int i = 0; i < 4; ++i) {
      #pragma unroll
      for (int r = 0; r < 4; ++r) {
        int v = m0 + wm + i * 16 + l4 * 4 + r;
        if (v < M) {
          float bv = bias[v];
          #pragma unroll
          for (int j = 0; j < 4; ++j) {
            int n = n0 + wn_ + j * 16 + l16;
            int bb = n / TT, tq = n - bb * TT;
            out[(size_t)bb * ((size_t)VV * TT) + (size_t)v * TT + tq] = acc[i][j][r] + bv;
          }
        }
      }
    }
  }
}

// ---------------- fused persistent LSTM (all 24 steps, flag barrier) ----------------
__global__ __launch_bounds__(512, 1) void lstm_seq_k(
    const ushort_t* __restrict__ Whh,    // [4096][1024] bf16
    const float* __restrict__ xgT,       // [24][4096][128] f32, bias included
    ushort_t* __restrict__ hs,           // [3072][1024] bf16, row = b*24+t
    int* __restrict__ bar)
{
  __shared__ f32x4 red[6][64][4];        // 24 KB
  const int tid = threadIdx.x, wid = tid >> 6, lane = tid & 63;
  const int l16 = lane & 15, l4 = lane >> 4;
  const int bid = blockIdx.x;
  const int jblk = bid & 63, mblk = bid >> 6;
  const int j0 = jblk * 16, m0 = mblk * 32;
  const int ks = wid >> 1;               // 0..3 (K quarter)
  const int msub = (wid & 1) * 16;
  int* flags = bar;
  int* rel = bar + 256;

  // hoist W_hh fragments into registers: 4 gates x 8 kc x bf16x8 = 128 VGPRs
  bf16x8 Breg[4][8];
  #pragma unroll
  for (int g = 0; g < 4; ++g) {
    const ushort_t* bp = Whh + ((size_t)(g * 1024 + j0 + l16) << 10) + ks * 256 + l4 * 8;
    #pragma unroll
    for (int kc = 0; kc < 8; ++kc)
      Breg[g][kc] = *reinterpret_cast<const bf16x8*>(bp + kc * 32);
  }
  const int arow = m0 + msub + l16;
  float c_reg[4] = {0.f, 0.f, 0.f, 0.f};

  for (int t = 0; t < TT; ++t) {
    f32x4 acc[4] = {};
    f32x4 xv[4];
    if (ks == 0) {
      const float* xp = xgT + ((size_t)(t * GG + j0 + l16)) * BB + m0 + msub + l4 * 4;
      #pragma unroll
      for (int g = 0; g < 4; ++g)
        xv[g] = *reinterpret_cast<const f32x4*>(xp + (size_t)g * 1024 * BB);
    }
    if (t > 0) {
      const u64* Ab = reinterpret_cast<const u64*>(
          hs + (((size_t)arow * TT + (t - 1)) << 10) + ks * 256 + l4 * 8);
      bf16x8 afs[8];
      #pragma unroll
      for (int kc = 0; kc < 8; ++kc) {
        union { u64 q[2]; bf16x8 v; } u;
        u.q[0] = __hip_atomic_load(Ab + kc * 8,     __ATOMIC_RELAXED, __HIP_MEMORY_SCOPE_AGENT);
        u.q[1] = __hip_atomic_load(Ab + kc * 8 + 1, __ATOMIC_RELAXED, __HIP_MEMORY_SCOPE_AGENT);
        afs[kc] = u.v;
      }
      #pragma unroll
      for (int kc = 0; kc < 8; ++kc)
        #pragma unroll
        for (int g = 0; g < 4; ++g)
          acc[g] = __builtin_amdgcn_mfma_f32_16x16x32_bf16(afs[kc], Breg[g][kc], acc[g], 0, 0, 0);
    }
    if (ks != 0) {
      int slot = (ks - 1) * 2 + (wid & 1);
      #pragma unroll
      for (int g = 0; g < 4; ++g) red[slot][lane][g] = acc[g];
    }
    __syncthreads();
    if (ks == 0) {
      #pragma unroll
      for (int s = 0; s < 3; ++s)
        #pragma unroll
        for (int g = 0; g < 4; ++g)
          acc[g] += red[s * 2 + (wid & 1)][lane][g];
      #pragma unroll
      for (int r = 0; r < 4; ++r) {
        int b = m0 + msub + l4 * 4 + r;
        float gi = acc[0][r] + xv[0][r];
        float gf = acc[1][r] + xv[1][r];
        float gg = acc[2][r] + xv[2][r];
        float go = acc[3][r] + xv[3][r];
        gi = 1.f / (1.f + expf(-gi));
        gf = 1.f / (1.f + expf(-gf));
        go = 1.f / (1.f + expf(-go));
        float cn = gf * c_reg[r] + gi * tanhf(gg);
        c_reg[r] = cn;
        float hn = go * tanhf(cn);
        unsigned hv = (unsigned)f2bf(hn);
        unsigned pv = (unsigned)__shfl_xor((int)hv, 1);
        if (!(l16 & 1)) {
          unsigned pk = (hv & 0xffffu) | (pv << 16);
          __hip_atomic_store(
              reinterpret_cast<unsigned*>(hs + (((size_t)b * TT + t) << 10) + j0 + l16),
              pk, __ATOMIC_RELAXED, __HIP_MEMORY_SCOPE_AGENT);
        }
      }
    }
    if (t < TT - 1) {
      __syncthreads();
      if (bid == 0) {
        if (wid == 0) {
          if (lane == 0)
            __hip_atomic_store(&flags[0], t + 1, __ATOMIC_RELAXED, __HIP_MEMORY_SCOPE_AGENT);
          for (;;) {
            int a0 = __hip_atomic_load(&flags[lane],       __ATOMIC_RELAXED, __HIP_MEMORY_SCOPE_AGENT);
            int a1 = __hip_atomic_load(&flags[lane +  64], __ATOMIC_RELAXED, __HIP_MEMORY_SCOPE_AGENT);
            int a2 = __hip_atomic_load(&flags[lane + 128], __ATOMIC_RELAXED, __HIP_MEMORY_SCOPE_AGENT);
            int a3 = __hip_atomic_load(&flags[lane + 192], __ATOMIC_RELAXED, __HIP_MEMORY_SCOPE_AGENT);
            int mn = min(min(a0, a1), min(a2, a3));
            if (__all(mn >= t + 1)) break;
            __builtin_amdgcn_s_sleep(2);
          }
          if (lane < 8)
            __hip_atomic_store(&rel[lane * 64], t + 1, __ATOMIC_RELAXED, __HIP_MEMORY_SCOPE_AGENT);
        }
      } else {
        if (tid == 0) {
          __hip_atomic_store(&flags[bid], t + 1, __ATOMIC_RELAXED, __HIP_MEMORY_SCOPE_AGENT);
          while (__hip_atomic_load(&rel[(bid & 7) * 64], __ATOMIC_RELAXED, __HIP_MEMORY_SCOPE_AGENT) < t + 1)
            __builtin_amdgcn_s_sleep(4);
        }
      }
      __syncthreads();
    }
  }
}

// ---------------- launcher ----------------

extern "C" void kernel_launch(void* const* d_in, const int* in_sizes, int n_in,
                              void* d_out, int out_size, void* d_ws, size_t ws_size,
                              hipStream_t stream) {
  const float* features = (const float*)d_in[0];
  const int*   captions = (const int*)d_in[1];
  const int*   pad_idx  = (const int*)d_in[2];
  const float* emb      = (const float*)d_in[3];
  const float* W_ih     = (const float*)d_in[4];
  const float* W_hh     = (const float*)d_in[5];
  const float* b_ih     = (const float*)d_in[6];
  const float* b_hh     = (const float*)d_in[7];
  const float* W_out    = (const float*)d_in[8];
  const float* b_out    = (const float*)d_in[9];
  float* out = (float*)d_out;

  char* w = (char*)d_ws;
  auto carve = [&](size_t bytes) {
    char* p = w;
    w += (bytes + 255) & ~(size_t)255;
    return p;
  };
  ushort_t* Wih_b  = (ushort_t*)carve((size_t)GG * HH * 2);
  ushort_t* Whh_b  = (ushort_t*)carve((size_t)GG * HH * 2);
  ushort_t* Wout_b = (ushort_t*)carve((size_t)30208 * HH * 2);  // padded to 236 tiles of 128
  ushort_t* xa     = (ushort_t*)carve((size_t)MM * HH * 2);
  float*    xgT    = (float*)carve((size_t)MM * GG * 4);        // [24][4096][128]
  ushort_t* hs     = (ushort_t*)carve((size_t)MM * HH * 2);
  float*    bsum   = (float*)carve((size_t)GG * 4);
  int*      bar    = (int*)carve(4096);

  cast_bf16_k<<<dim3(1024), 256, 0, stream>>>(W_ih, Wih_b, GG * HH / 4);
  cast_bf16_k<<<dim3(1024), 256, 0, stream>>>(W_hh, Whh_b, GG * HH / 4);
  cast_bf16_k<<<dim3(2048), 256, 0, stream>>>(W_out, Wout_b, VV * HH / 4);
  bias_sum_k<<<dim3(16), 256, 0, stream>>>(b_ih, b_hh, bsum);
  build_xa_k<<<dim3(MM), 256, 0, stream>>>(emb, captions, pad_idx, features, xa);
  zero_bar_k<<<dim3(1), 256, 0, stream>>>(bar);

  // xgT: grid 768 = 8 XCDs x (12 m x 8 n); xn_cnt=4 -> B slice 2MB L2-resident
  gemm_bt<0><<<dim3(768), 256, 0, stream>>>(xa, Wih_b, bsum, xgT, MM, GG, 8, 4);

  // all 24 LSTM steps in one persistent kernel (h history in hs)
  lstm_seq_k<<<dim3(256), 512, 0, stream>>>(Whh_b, xgT, hs, bar);

  // logits: grid 5664 = 8 XCDs x (59 m x 12 n); xn_cnt=2 -> hs slice 3MB L2-resident
  gemm_bt<1><<<dim3(5664), 256, 0, stream>>>(Wout_b, hs, b_out, out, VV, MM, 12, 2);
}

// Round 6
// 594.594 us; speedup vs baseline: 1.9876x; 1.0402x over previous
//
#include <hip/hip_runtime.h>
#include <hip/hip_bf16.h>
#include <math.h>

typedef unsigned short ushort_t;
typedef unsigned long long u64;
typedef __bf16 bf16x8 __attribute__((ext_vector_type(8)));
typedef float f32x4 __attribute__((ext_vector_type(4)));

#define BB 128
#define TT 24
#define EE 512
#define VV 30000
#define HH 1024
#define GG 4096
#define MM (BB*TT)   // 3072 rows, m = t*128 + b
#define MPAD 30208   // 118 tiles of 256

static __device__ __forceinline__ ushort_t f2bf(float x) {
  __hip_bfloat16 h = __float2bfloat16(x);
  return __builtin_bit_cast(ushort_t, h);
}

// async global->LDS, 16B per lane; lds base must be wave-uniform
static __device__ __forceinline__ void gld_lds16(const void* g, void* l) {
  __builtin_amdgcn_global_load_lds((const __attribute__((address_space(1))) void*)g,
                                   (__attribute__((address_space(3))) void*)l, 16, 0, 0);
}

// ---------------- prep kernels ----------------

__global__ void cast_bf16_k(const float* __restrict__ s, ushort_t* __restrict__ d, int n4) {
  int i = blockIdx.x * blockDim.x + threadIdx.x;
  int stride = gridDim.x * blockDim.x;
  for (; i < n4; i += stride) {
    float4 v = reinterpret_cast<const float4*>(s)[i];
    ushort4 o;
    o.x = f2bf(v.x); o.y = f2bf(v.y); o.z = f2bf(v.z); o.w = f2bf(v.w);
    reinterpret_cast<ushort4*>(d)[i] = o;
  }
}

__global__ void bias_sum_k(const float* __restrict__ bi, const float* __restrict__ bh,
                           float* __restrict__ bs) {
  int i = blockIdx.x * blockDim.x + threadIdx.x;
  if (i < GG) bs[i] = bi[i] + bh[i];
}

__global__ void build_xa_k(const float* __restrict__ emb, const int* __restrict__ captions,
                           const int* __restrict__ pad_idx, const float* __restrict__ features,
                           ushort_t* __restrict__ xa) {
  int row = blockIdx.x;          // 0..3071, row = t*128+b
  int t = row >> 7;
  int b = row & 127;
  int cap = (t == 0) ? pad_idx[0] : captions[b * TT + (t - 1)];
  const float* s0 = emb + (size_t)cap * EE;
  const float* s1 = features + (size_t)b * EE;
  ushort_t* d = xa + (size_t)row * (2 * EE);
  for (int e = threadIdx.x; e < EE; e += 256) {
    d[e] = f2bf(s0[e]);
    d[EE + e] = f2bf(s1[e]);
  }
}

__global__ void zero_bar_k(int* __restrict__ bar) {
  for (int i = threadIdx.x; i < 768; i += 256)
    __hip_atomic_store(&bar[i], 0, __ATOMIC_RELAXED, __HIP_MEMORY_SCOPE_AGENT);
}

// ---------------- GEMM 128x128 (xg only), round-5 structure ----------------
__global__ __launch_bounds__(256) void gemm_xg(
    const ushort_t* __restrict__ A,
    const ushort_t* __restrict__ Bm,
    const float* __restrict__ bias,
    float* __restrict__ out,
    int M, int N, int swn, int xn_cnt)
{
  constexpr int K = 1024;
  __shared__ __align__(16) ushort_t As[2][8192];
  __shared__ __align__(16) ushort_t Bs[2][8192];
  const int bid = blockIdx.x;
  const int xcd = bid & 7, c = bid >> 3;
  const int xn = xcd % xn_cnt, xm = xcd / xn_cnt;
  const int nblk = xn * swn + (c % swn);
  const int n0 = nblk * 128;
  const int m0 = (xm * ((gridDim.x >> 3) / swn) + (c / swn)) * 128;
  const int tid = threadIdx.x, wid = tid >> 6, lane = tid & 63;
  const int wm = (wid >> 1) * 64, wn_ = (wid & 1) * 64;
  const int srow = lane >> 3;
  const int scolsw = ((lane & 7) ^ srow) * 8;
  const int rr = lane & 15, l4 = lane >> 4;
  const int swz = (rr & 7) << 4;
  const int col0 = (((l4 << 4) ^ swz) >> 1);
  const int col1 = (((64 | (l4 << 4)) ^ swz) >> 1);

  f32x4 acc[4][4] = {};

  auto stage = [&](int buf, int k0) {
    #pragma unroll
    for (int p = 0; p < 4; ++p) {
      int ch = p * 4 + wid;
      int row = ch * 8 + srow;
      gld_lds16(A + (size_t)(m0 + row) * K + k0 + scolsw, &As[buf][ch * 512]);
      gld_lds16(Bm + (size_t)(n0 + row) * K + k0 + scolsw, &Bs[buf][ch * 512]);
    }
  };

  stage(0, 0);
  int cur = 0;
  for (int tau = 0; tau < 16; ++tau) {
    if (tau < 15) {
      stage(cur ^ 1, (tau + 1) * 64);
      asm volatile("s_waitcnt vmcnt(8)" ::: "memory");
    } else {
      asm volatile("s_waitcnt vmcnt(0)" ::: "memory");
    }
    __builtin_amdgcn_s_barrier();
    const ushort_t* Ac = As[cur];
    const ushort_t* Bc = Bs[cur];
    #pragma unroll
    for (int kk = 0; kk < 2; ++kk) {
      const int ce = kk ? col1 : col0;
      bf16x8 af[4], bfv[4];
      #pragma unroll
      for (int i = 0; i < 4; ++i)
        af[i] = *reinterpret_cast<const bf16x8*>(Ac + (wm + i * 16 + rr) * 64 + ce);
      #pragma unroll
      for (int j = 0; j < 4; ++j)
        bfv[j] = *reinterpret_cast<const bf16x8*>(Bc + (wn_ + j * 16 + rr) * 64 + ce);
      #pragma unroll
      for (int i = 0; i < 4; ++i)
        #pragma unroll
        for (int j = 0; j < 4; ++j)
          acc[i][j] = __builtin_amdgcn_mfma_f32_16x16x32_bf16(af[i], bfv[j], acc[i][j], 0, 0, 0);
    }
    asm volatile("" ::: "memory");
    __builtin_amdgcn_s_barrier();
    cur ^= 1;
  }

  const int l16 = lane & 15;
  const int t_blk = m0 >> 7;
  #pragma unroll
  for (int i = 0; i < 4; ++i) {
    #pragma unroll
    for (int j = 0; j < 4; ++j) {
      int n = n0 + wn_ + j * 16 + l16;
      float bv = bias[n];
      #pragma unroll
      for (int r = 0; r < 4; ++r) {
        int b = wm + i * 16 + l4 * 4 + r;
        out[((size_t)t_blk * GG + n) * BB + b] = acc[i][j][r] + bv;
      }
    }
  }
}

// ---------------- GEMM 256x256 8-phase (logits) ----------------
// A = Wout_b [30208][1024], B = hs [3072][1024]; out[b*V*T + v*T + t] + bias[v]
// 512 threads = 8 waves (2M x 4N). acc[8][4]; LDS 2 x (A 32K + B 32K) = 128 KB.
// Chunks per K-tile: SA1(ct0): A rows {0-63,128-191}; SB1(ct1): B rows {0-31,64-95,128-159,192-223};
// SB2(ct2): other B strips; SA2(ct3): A rows {64-127,192-255}.
// Phase p computes quadrant (mh=p>>1, nh=p&1); stages chunk p of K-tile g+1.
__global__ __launch_bounds__(512) void gemm256_logits(
    const ushort_t* __restrict__ A,
    const ushort_t* __restrict__ Bm,
    const float* __restrict__ bias,
    float* __restrict__ out)
{
  constexpr int K = 1024, NT = 16;
  __shared__ __align__(16) ushort_t As[2][16384];
  __shared__ __align__(16) ushort_t Bs[2][16384];
  const int bid = blockIdx.x;
  const int g = (bid & 7) * 177 + (bid >> 3);       // XCD-contiguous tiles
  const int m0 = (g / 12) * 256, n0 = (g % 12) * 256;
  const int tid = threadIdx.x, wid = tid >> 6, lane = tid & 63;
  const int wm2 = wid >> 2, wn4 = wid & 3;
  const int rr = lane & 15, l4 = lane >> 4;
  const int col80 = (l4 ^ (rr & 7)) * 8;            // kk=0 LDS col (elements, swizzled)
  const int col81 = ((l4 + 4) ^ (rr & 7)) * 8;      // kk=1
  const int la0 = rr + wm2 * 64;                    // A chunk-local row base
  const int lb0 = wn4 * 32 + rr;                    // B chunk-local row base

  f32x4 acc[8][4] = {};

  // stage chunk ct of K-tile kt into buffer buf (2 x gld_lds16 per thread)
  auto stage = [&](int buf, int kt, int ct) {
    const int k0 = kt * 64;
    #pragma unroll
    for (int l = 0; l < 2; ++l) {
      int f = l * 512 + tid;
      int lr = f >> 3;
      int ecol = k0 + (((f & 7) ^ (lr & 7)) * 8);   // inverse-swizzled source col
      if (ct == 0 || ct == 3) {
        int cc = (ct == 3);
        int grow = (lr & 63) + ((lr >> 6) << 7) + cc * 64;
        gld_lds16(A + (size_t)(m0 + grow) * K + ecol,
                  &As[buf][cc * 8192 + (l * 512 + wid * 64) * 8]);
      } else {
        int cc = ct - 1;
        int grow = ((lr >> 5) << 6) + cc * 32 + (lr & 31);
        gld_lds16(Bm + (size_t)(n0 + grow) * K + ecol,
                  &Bs[buf][cc * 8192 + (l * 512 + wid * 64) * 8]);
      }
    }
  };

  // prologue: stage all 4 chunks of kt0 into buf0; gate first two chunks
  #pragma unroll
  for (int p = 0; p < 4; ++p) stage(0, 0, p);
  asm volatile("s_waitcnt vmcnt(4)" ::: "memory");
  __builtin_amdgcn_s_barrier();

  int cur = 0;
  for (int g2 = 0; g2 < NT; ++g2) {
    const int buf = cur, bufn = cur ^ 1;
    const int ktn = (g2 + 1 < NT) ? g2 + 1 : g2;    // last iter: harmless re-stage
    bf16x8 aF[4][2], bF[2][2];
    #pragma unroll
    for (int p = 0; p < 4; ++p) {
      stage(bufn, ktn, p);
      if ((p & 1) == 0) {                           // load A half (mh = p>>1)
        #pragma unroll
        for (int mi = 0; mi < 4; ++mi) {
          const ushort_t* ab = &As[buf][(p >> 1) * 8192 + (la0 + mi * 16) * 64];
          aF[mi][0] = *reinterpret_cast<const bf16x8*>(ab + col80);
          aF[mi][1] = *reinterpret_cast<const bf16x8*>(ab + col81);
        }
      }
      #pragma unroll
      for (int ni = 0; ni < 2; ++ni) {              // B frags (nf = (p&1)*2+ni)
        const int nf = (p & 1) * 2 + ni;
        const ushort_t* bb2 = &Bs[buf][(nf >> 1) * 8192 + (lb0 + (nf & 1) * 16) * 64];
        bF[ni][0] = *reinterpret_cast<const bf16x8*>(bb2 + col80);
        bF[ni][1] = *reinterpret_cast<const bf16x8*>(bb2 + col81);
      }
      asm volatile("s_waitcnt lgkmcnt(0)" ::: "memory");
      __builtin_amdgcn_sched_barrier(0);
      __builtin_amdgcn_s_setprio(1);
      #pragma unroll
      for (int mi = 0; mi < 4; ++mi)
        #pragma unroll
        for (int ni = 0; ni < 2; ++ni) {
          f32x4 a = acc[(p >> 1) * 4 + mi][(p & 1) * 2 + ni];
          a = __builtin_amdgcn_mfma_f32_16x16x32_bf16(aF[mi][0], bF[ni][0], a, 0, 0, 0);
          a = __builtin_amdgcn_mfma_f32_16x16x32_bf16(aF[mi][1], bF[ni][1], a, 0, 0, 0);
          acc[(p >> 1) * 4 + mi][(p & 1) * 2 + ni] = a;
        }
      __builtin_amdgcn_s_setprio(0);
      if (p != 2) asm volatile("s_waitcnt vmcnt(4)" ::: "memory");
      __builtin_amdgcn_s_barrier();
    }
    cur ^= 1;
  }
  asm volatile("s_waitcnt vmcnt(0)" ::: "memory");  // drain before LDS dealloc

  // epilogue: v = m0 + wm2*128 + mf*16 + l4*4 + r ; n = n0 + wn4*64 + nf*16 + rr
  const int vbase = m0 + wm2 * 128;
  const int nbase = n0 + wn4 * 64;
  #pragma unroll
  for (int mf = 0; mf < 8; ++mf) {
    #pragma unroll
    for (int r = 0; r < 4; ++r) {
      int v = vbase + mf * 16 + l4 * 4 + r;
      if (v < VV) {
        float bv = bias[v];
        #pragma unroll
        for (int nf = 0; nf < 4; ++nf) {
          int n = nbase + nf * 16 + rr;
          int bb = n / TT, tq = n - bb * TT;
          out[(size_t)bb * ((size_t)VV * TT) + (size_t)v * TT + tq] = acc[mf][nf][r] + bv;
        }
      }
    }
  }
}

// ---------------- fused persistent LSTM (all 24 steps, flag barrier) ----------------
__global__ __launch_bounds__(512, 1) void lstm_seq_k(
    const ushort_t* __restrict__ Whh,    // [4096][1024] bf16
    const float* __restrict__ xgT,       // [24][4096][128] f32, bias included
    ushort_t* __restrict__ hs,           // [3072][1024] bf16, row = b*24+t
    int* __restrict__ bar)
{
  __shared__ f32x4 red[6][64][4];        // 24 KB
  const int tid = threadIdx.x, wid = tid >> 6, lane = tid & 63;
  const int l16 = lane & 15, l4 = lane >> 4;
  const int bid = blockIdx.x;
  const int jblk = bid & 63, mblk = bid >> 6;
  const int j0 = jblk * 16, m0 = mblk * 32;
  const int ks = wid >> 1;
  const int msub = (wid & 1) * 16;
  int* flags = bar;
  int* rel = bar + 256;

  bf16x8 Breg[4][8];
  #pragma unroll
  for (int g = 0; g < 4; ++g) {
    const ushort_t* bp = Whh + ((size_t)(g * 1024 + j0 + l16) << 10) + ks * 256 + l4 * 8;
    #pragma unroll
    for (int kc = 0; kc < 8; ++kc)
      Breg[g][kc] = *reinterpret_cast<const bf16x8*>(bp + kc * 32);
  }
  const int arow = m0 + msub + l16;
  float c_reg[4] = {0.f, 0.f, 0.f, 0.f};

  for (int t = 0; t < TT; ++t) {
    f32x4 acc[4] = {};
    f32x4 xv[4];
    if (ks == 0) {
      const float* xp = xgT + ((size_t)(t * GG + j0 + l16)) * BB + m0 + msub + l4 * 4;
      #pragma unroll
      for (int g = 0; g < 4; ++g)
        xv[g] = *reinterpret_cast<const f32x4*>(xp + (size_t)g * 1024 * BB);
    }
    if (t > 0) {
      const u64* Ab = reinterpret_cast<const u64*>(
          hs + (((size_t)arow * TT + (t - 1)) << 10) + ks * 256 + l4 * 8);
      bf16x8 afs[8];
      #pragma unroll
      for (int kc = 0; kc < 8; ++kc) {
        union { u64 q[2]; bf16x8 v; } u;
        u.q[0] = __hip_atomic_load(Ab + kc * 8,     __ATOMIC_RELAXED, __HIP_MEMORY_SCOPE_AGENT);
        u.q[1] = __hip_atomic_load(Ab + kc * 8 + 1, __ATOMIC_RELAXED, __HIP_MEMORY_SCOPE_AGENT);
        afs[kc] = u.v;
      }
      #pragma unroll
      for (int kc = 0; kc < 8; ++kc)
        #pragma unroll
        for (int g = 0; g < 4; ++g)
          acc[g] = __builtin_amdgcn_mfma_f32_16x16x32_bf16(afs[kc], Breg[g][kc], acc[g], 0, 0, 0);
    }
    if (ks != 0) {
      int slot = (ks - 1) * 2 + (wid & 1);
      #pragma unroll
      for (int g = 0; g < 4; ++g) red[slot][lane][g] = acc[g];
    }
    __syncthreads();
    if (ks == 0) {
      #pragma unroll
      for (int s = 0; s < 3; ++s)
        #pragma unroll
        for (int g = 0; g < 4; ++g)
          acc[g] += red[s * 2 + (wid & 1)][lane][g];
      #pragma unroll
      for (int r = 0; r < 4; ++r) {
        int b = m0 + msub + l4 * 4 + r;
        float gi = acc[0][r] + xv[0][r];
        float gf = acc[1][r] + xv[1][r];
        float gg = acc[2][r] + xv[2][r];
        float go = acc[3][r] + xv[3][r];
        gi = 1.f / (1.f + expf(-gi));
        gf = 1.f / (1.f + expf(-gf));
        go = 1.f / (1.f + expf(-go));
        float cn = gf * c_reg[r] + gi * tanhf(gg);
        c_reg[r] = cn;
        float hn = go * tanhf(cn);
        unsigned hv = (unsigned)f2bf(hn);
        unsigned pv = (unsigned)__shfl_xor((int)hv, 1);
        if (!(l16 & 1)) {
          unsigned pk = (hv & 0xffffu) | (pv << 16);
          __hip_atomic_store(
              reinterpret_cast<unsigned*>(hs + (((size_t)b * TT + t) << 10) + j0 + l16),
              pk, __ATOMIC_RELAXED, __HIP_MEMORY_SCOPE_AGENT);
        }
      }
    }
    if (t < TT - 1) {
      __syncthreads();
      if (bid == 0) {
        if (wid == 0) {
          if (lane == 0)
            __hip_atomic_store(&flags[0], t + 1, __ATOMIC_RELAXED, __HIP_MEMORY_SCOPE_AGENT);
          for (;;) {
            int a0 = __hip_atomic_load(&flags[lane],       __ATOMIC_RELAXED, __HIP_MEMORY_SCOPE_AGENT);
            int a1 = __hip_atomic_load(&flags[lane +  64], __ATOMIC_RELAXED, __HIP_MEMORY_SCOPE_AGENT);
            int a2 = __hip_atomic_load(&flags[lane + 128], __ATOMIC_RELAXED, __HIP_MEMORY_SCOPE_AGENT);
            int a3 = __hip_atomic_load(&flags[lane + 192], __ATOMIC_RELAXED, __HIP_MEMORY_SCOPE_AGENT);
            int mn = min(min(a0, a1), min(a2, a3));
            if (__all(mn >= t + 1)) break;
            __builtin_amdgcn_s_sleep(2);
          }
          if (lane < 8)
            __hip_atomic_store(&rel[lane * 64], t + 1, __ATOMIC_RELAXED, __HIP_MEMORY_SCOPE_AGENT);
        }
      } else {
        if (tid == 0) {
          __hip_atomic_store(&flags[bid], t + 1, __ATOMIC_RELAXED, __HIP_MEMORY_SCOPE_AGENT);
          while (__hip_atomic_load(&rel[(bid & 7) * 64], __ATOMIC_RELAXED, __HIP_MEMORY_SCOPE_AGENT) < t + 1)
            __builtin_amdgcn_s_sleep(4);
        }
      }
      __syncthreads();
    }
  }
}

// ---------------- launcher ----------------

extern "C" void kernel_launch(void* const* d_in, const int* in_sizes, int n_in,
                              void* d_out, int out_size, void* d_ws, size_t ws_size,
                              hipStream_t stream) {
  const float* features = (const float*)d_in[0];
  const int*   captions = (const int*)d_in[1];
  const int*   pad_idx  = (const int*)d_in[2];
  const float* emb      = (const float*)d_in[3];
  const float* W_ih     = (const float*)d_in[4];
  const float* W_hh     = (const float*)d_in[5];
  const float* b_ih     = (const float*)d_in[6];
  const float* b_hh     = (const float*)d_in[7];
  const float* W_out    = (const float*)d_in[8];
  const float* b_out    = (const float*)d_in[9];
  float* out = (float*)d_out;

  char* w = (char*)d_ws;
  auto carve = [&](size_t bytes) {
    char* p = w;
    w += (bytes + 255) & ~(size_t)255;
    return p;
  };
  ushort_t* Wih_b  = (ushort_t*)carve((size_t)GG * HH * 2);
  ushort_t* Whh_b  = (ushort_t*)carve((size_t)GG * HH * 2);
  ushort_t* Wout_b = (ushort_t*)carve((size_t)MPAD * HH * 2);
  ushort_t* xa     = (ushort_t*)carve((size_t)MM * HH * 2);
  float*    xgT    = (float*)carve((size_t)MM * GG * 4);        // [24][4096][128]
  ushort_t* hs     = (ushort_t*)carve((size_t)MM * HH * 2);
  float*    bsum   = (float*)carve((size_t)GG * 4);
  int*      bar    = (int*)carve(4096);

  cast_bf16_k<<<dim3(1024), 256, 0, stream>>>(W_ih, Wih_b, GG * HH / 4);
  cast_bf16_k<<<dim3(1024), 256, 0, stream>>>(W_hh, Whh_b, GG * HH / 4);
  cast_bf16_k<<<dim3(2048), 256, 0, stream>>>(W_out, Wout_b, VV * HH / 4);
  bias_sum_k<<<dim3(16), 256, 0, stream>>>(b_ih, b_hh, bsum);
  build_xa_k<<<dim3(MM), 256, 0, stream>>>(emb, captions, pad_idx, features, xa);
  zero_bar_k<<<dim3(1), 256, 0, stream>>>(bar);

  // xgT: grid 768 = 8 XCDs x (12 m x 8 n)
  gemm_xg<<<dim3(768), 256, 0, stream>>>(xa, Wih_b, bsum, xgT, MM, GG, 8, 4);

  // all 24 LSTM steps in one persistent kernel
  lstm_seq_k<<<dim3(256), 512, 0, stream>>>(Whh_b, xgT, hs, bar);

  // logits: 118 x 12 tiles of 256 = 1416 = 8 x 177
  gemm256_logits<<<dim3(1416), 512, 0, stream>>>(Wout_b, hs, b_out, out);
}

// Round 8
// 563.315 us; speedup vs baseline: 2.0980x; 1.0555x over previous
//
#include <hip/hip_runtime.h>
#include <hip/hip_bf16.h>
#include <math.h>

typedef unsigned short ushort_t;
typedef unsigned long long u64;
typedef __bf16 bf16x8 __attribute__((ext_vector_type(8)));
typedef float f32x4 __attribute__((ext_vector_type(4)));

#define BB 128
#define TT 24
#define EE 512
#define VV 30000
#define HH 1024
#define GG 4096
#define MM (BB*TT)   // 3072 rows, m = t*128 + b
#define MPAD 30208   // 118 tiles of 256

static __device__ __forceinline__ ushort_t f2bf(float x) {
  __hip_bfloat16 h = __float2bfloat16(x);
  return __builtin_bit_cast(ushort_t, h);
}

// async global->LDS, 16B per lane; lds base must be wave-uniform
static __device__ __forceinline__ void gld_lds16(const void* g, void* l) {
  __builtin_amdgcn_global_load_lds((const __attribute__((address_space(1))) void*)g,
                                   (__attribute__((address_space(3))) void*)l, 16, 0, 0);
}

// ---------------- prep kernels ----------------

__global__ void cast_bf16_k(const float* __restrict__ s, ushort_t* __restrict__ d, int n4) {
  int i = blockIdx.x * blockDim.x + threadIdx.x;
  int stride = gridDim.x * blockDim.x;
  for (; i < n4; i += stride) {
    float4 v = reinterpret_cast<const float4*>(s)[i];
    ushort4 o;
    o.x = f2bf(v.x); o.y = f2bf(v.y); o.z = f2bf(v.z); o.w = f2bf(v.w);
    reinterpret_cast<ushort4*>(d)[i] = o;
  }
}

__global__ void bias_sum_k(const float* __restrict__ bi, const float* __restrict__ bh,
                           float* __restrict__ bs) {
  int i = blockIdx.x * blockDim.x + threadIdx.x;
  if (i < GG) bs[i] = bi[i] + bh[i];
}

__global__ void build_xa_k(const float* __restrict__ emb, const int* __restrict__ captions,
                           const int* __restrict__ pad_idx, const float* __restrict__ features,
                           ushort_t* __restrict__ xa) {
  int row = blockIdx.x;          // 0..3071, row = t*128+b
  int t = row >> 7;
  int b = row & 127;
  int cap = (t == 0) ? pad_idx[0] : captions[b * TT + (t - 1)];
  const float* s0 = emb + (size_t)cap * EE;
  const float* s1 = features + (size_t)b * EE;
  ushort_t* d = xa + (size_t)row * (2 * EE);
  for (int e = threadIdx.x; e < EE; e += 256) {
    d[e] = f2bf(s0[e]);
    d[EE + e] = f2bf(s1[e]);
  }
}

__global__ void zero_bar_k(int* __restrict__ bar) {
  for (int i = threadIdx.x; i < 768; i += 256)
    __hip_atomic_store(&bar[i], 0, __ATOMIC_RELAXED, __HIP_MEMORY_SCOPE_AGENT);
}

// ---------------- GEMM 128x128 (xg only), round-5 structure ----------------
__global__ __launch_bounds__(256) void gemm_xg(
    const ushort_t* __restrict__ A,
    const ushort_t* __restrict__ Bm,
    const float* __restrict__ bias,
    float* __restrict__ out,
    int M, int N, int swn, int xn_cnt)
{
  constexpr int K = 1024;
  __shared__ __align__(16) ushort_t As[2][8192];
  __shared__ __align__(16) ushort_t Bs[2][8192];
  const int bid = blockIdx.x;
  const int xcd = bid & 7, c = bid >> 3;
  const int xn = xcd % xn_cnt, xm = xcd / xn_cnt;
  const int nblk = xn * swn + (c % swn);
  const int n0 = nblk * 128;
  const int m0 = (xm * ((gridDim.x >> 3) / swn) + (c / swn)) * 128;
  const int tid = threadIdx.x, wid = tid >> 6, lane = tid & 63;
  const int wm = (wid >> 1) * 64, wn_ = (wid & 1) * 64;
  const int srow = lane >> 3;
  const int scolsw = ((lane & 7) ^ srow) * 8;
  const int rr = lane & 15, l4 = lane >> 4;
  const int swz = (rr & 7) << 4;
  const int col0 = (((l4 << 4) ^ swz) >> 1);
  const int col1 = (((64 | (l4 << 4)) ^ swz) >> 1);

  f32x4 acc[4][4] = {};

  auto stage = [&](int buf, int k0) {
    #pragma unroll
    for (int p = 0; p < 4; ++p) {
      int ch = p * 4 + wid;
      int row = ch * 8 + srow;
      gld_lds16(A + (size_t)(m0 + row) * K + k0 + scolsw, &As[buf][ch * 512]);
      gld_lds16(Bm + (size_t)(n0 + row) * K + k0 + scolsw, &Bs[buf][ch * 512]);
    }
  };

  stage(0, 0);
  int cur = 0;
  for (int tau = 0; tau < 16; ++tau) {
    if (tau < 15) {
      stage(cur ^ 1, (tau + 1) * 64);
      asm volatile("s_waitcnt vmcnt(8)" ::: "memory");
    } else {
      asm volatile("s_waitcnt vmcnt(0)" ::: "memory");
    }
    __builtin_amdgcn_s_barrier();
    const ushort_t* Ac = As[cur];
    const ushort_t* Bc = Bs[cur];
    #pragma unroll
    for (int kk = 0; kk < 2; ++kk) {
      const int ce = kk ? col1 : col0;
      bf16x8 af[4], bfv[4];
      #pragma unroll
      for (int i = 0; i < 4; ++i)
        af[i] = *reinterpret_cast<const bf16x8*>(Ac + (wm + i * 16 + rr) * 64 + ce);
      #pragma unroll
      for (int j = 0; j < 4; ++j)
        bfv[j] = *reinterpret_cast<const bf16x8*>(Bc + (wn_ + j * 16 + rr) * 64 + ce);
      #pragma unroll
      for (int i = 0; i < 4; ++i)
        #pragma unroll
        for (int j = 0; j < 4; ++j)
          acc[i][j] = __builtin_amdgcn_mfma_f32_16x16x32_bf16(af[i], bfv[j], acc[i][j], 0, 0, 0);
    }
    asm volatile("" ::: "memory");
    __builtin_amdgcn_s_barrier();
    cur ^= 1;
  }

  const int l16 = lane & 15;
  const int t_blk = m0 >> 7;
  #pragma unroll
  for (int i = 0; i < 4; ++i) {
    #pragma unroll
    for (int j = 0; j < 4; ++j) {
      int n = n0 + wn_ + j * 16 + l16;
      float bv = bias[n];
      #pragma unroll
      for (int r = 0; r < 4; ++r) {
        int b = wm + i * 16 + l4 * 4 + r;
        out[((size_t)t_blk * GG + n) * BB + b] = acc[i][j][r] + bv;
      }
    }
  }
}

// ---------------- GEMM 256x256, deep-pipelined 4-phase/K-tile (logits) ----------------
// A = Wout_b [30208][1024], B = hs [3072][1024]; out[b*V*T + v*T + t] + bias[v]
// 512 threads = 8 waves (2M x 4N); per-wave 128x64 out = acc[8][4].
// CHUNKS (wave-decomposition-aligned, as in the verified round-6 staging):
//   ctA0: A rows {0-63, 128-191}   -> read Ph1 (mf 0..3, both wm2)
//   ctB0: B rows {w*64+0..31  ∀w}  -> read Ph1 (nf 0,1)
//   ctB1: B rows {w*64+32..63 ∀w}  -> read Ph2 (nf 2,3)
//   ctA1: A rows {64-127, 192-255} -> read Ph3 (mf 4..7)
// Stage order per tile g (into buf^1, tile g+1): Ph1 ctA0, Ph2 ctB0, Ph3 ctB1, Ph4 ctA1.
// Wait ledger (2 loads/stage, FIFO): vmcnt(4) at ends of Ph1 (lands ctB1 g), Ph2 (lands ctA1 g),
// Ph4 (lands ctA0,ctB0 g+1). No wait at Ph3. Outstanding never < 4; depth >= 3 phases.
__global__ __launch_bounds__(512) void gemm256_logits(
    const ushort_t* __restrict__ A,
    const ushort_t* __restrict__ Bm,
    const float* __restrict__ bias,
    float* __restrict__ out)
{
  constexpr int K = 1024, NT = 16;
  __shared__ __align__(16) ushort_t As[2][16384];
  __shared__ __align__(16) ushort_t Bs[2][16384];
  const int bid = blockIdx.x;
  const int g = (bid & 7) * 177 + (bid >> 3);       // XCD-contiguous tiles
  const int m0 = (g / 12) * 256, n0 = (g % 12) * 256;
  const int tid = threadIdx.x, wid = tid >> 6, lane = tid & 63;
  const int wm2 = wid >> 2, wn4 = wid & 3;
  const int rr = lane & 15, l4 = lane >> 4;

  f32x4 acc[8][4] = {};   // [mf 0..7][nf 0..3]

  // stage chunk ct of K-tile kt into buf. ct: 0=ctA0, 1=ctB0, 2=ctB1, 3=ctA1
  auto stage = [&](int buf, int kt, int ct) {
    const int k0 = kt * 64;
    #pragma unroll
    for (int l = 0; l < 2; ++l) {
      int f = l * 512 + tid;                        // slot 0..1023
      int lr = f >> 3;                              // chunk-local row 0..127
      int ecol = k0 + (((f & 7) ^ (lr & 7)) * 8);   // inverse-swizzled source granule
      if (ct == 0 || ct == 3) {
        int cc = (ct == 3);
        int grow = (lr & 63) + ((lr >> 6) << 7) + cc * 64;
        gld_lds16(A + (size_t)(m0 + grow) * K + ecol,
                  &As[buf][cc * 8192 + (l * 512 + wid * 64) * 8]);
      } else {
        int cc = ct - 1;
        int grow = ((lr >> 5) << 6) + cc * 32 + (lr & 31);
        gld_lds16(Bm + (size_t)(n0 + grow) * K + ecol,
                  &Bs[buf][cc * 8192 + (l * 512 + wid * 64) * 8]);
      }
    }
  };
  // frag reads (swizzled). rdA: chunk mf>>2, local row wm2*64 + (mf&3)*16 + rr
  auto rdA = [&](int buf, int mf, int kk) -> bf16x8 {
    int rl = wm2 * 64 + (mf & 3) * 16 + rr;
    return *reinterpret_cast<const bf16x8*>(
        &As[buf][(mf >> 2) * 8192 + rl * 64 + (((kk * 4 + l4) ^ (rr & 7)) * 8)]);
  };
  // rdB: chunk nf>>1, local row wn4*32 + (nf&1)*16 + rr
  auto rdB = [&](int buf, int nf, int kk) -> bf16x8 {
    int rl = wn4 * 32 + (nf & 1) * 16 + rr;
    return *reinterpret_cast<const bf16x8*>(
        &Bs[buf][(nf >> 1) * 8192 + rl * 64 + (((kk * 4 + l4) ^ (rr & 7)) * 8)]);
  };

  // prologue: stage all 4 chunks of tile 0; vmcnt(4) lands ctA0,ctB0 (Ph1's reads)
  #pragma unroll
  for (int hh = 0; hh < 4; ++hh) stage(0, 0, hh);
  asm volatile("s_waitcnt vmcnt(4)" ::: "memory");
  __builtin_amdgcn_s_barrier();

  bf16x8 aF[4][2], bF[2][2], bF2[2][2];
  int cur = 0;
  for (int g2 = 0; g2 < NT; ++g2) {
    const int buf = cur, bufn = cur ^ 1;
    const int ktn = (g2 + 1 < NT) ? g2 + 1 : g2;   // last tile: harmless self re-stage
    // ---------------- Phase 1: Q(mf 0..3, nf 0..1) ----------------
    #pragma unroll
    for (int mf = 0; mf < 4; ++mf) { aF[mf][0] = rdA(buf, mf, 0); aF[mf][1] = rdA(buf, mf, 1); }
    #pragma unroll
    for (int nf = 0; nf < 2; ++nf) { bF[nf][0] = rdB(buf, nf, 0); bF[nf][1] = rdB(buf, nf, 1); }
    stage(bufn, ktn, 0);
    __builtin_amdgcn_s_barrier();
    asm volatile("s_waitcnt lgkmcnt(0)" ::: "memory");
    __builtin_amdgcn_sched_barrier(0);
    __builtin_amdgcn_s_setprio(1);
    #pragma unroll
    for (int mf = 0; mf < 4; ++mf)
      #pragma unroll
      for (int nf = 0; nf < 2; ++nf) {
        acc[mf][nf] = __builtin_amdgcn_mfma_f32_16x16x32_bf16(aF[mf][0], bF[nf][0], acc[mf][nf], 0, 0, 0);
        acc[mf][nf] = __builtin_amdgcn_mfma_f32_16x16x32_bf16(aF[mf][1], bF[nf][1], acc[mf][nf], 0, 0, 0);
      }
    __builtin_amdgcn_s_setprio(0);
    asm volatile("s_waitcnt vmcnt(4)" ::: "memory");
    __builtin_amdgcn_s_barrier();
    // ---------------- Phase 2: Q(mf 0..3, nf 2..3) ----------------
    #pragma unroll
    for (int nf = 0; nf < 2; ++nf) { bF2[nf][0] = rdB(buf, 2 + nf, 0); bF2[nf][1] = rdB(buf, 2 + nf, 1); }
    stage(bufn, ktn, 1);
    __builtin_amdgcn_s_barrier();
    asm volatile("s_waitcnt lgkmcnt(0)" ::: "memory");
    __builtin_amdgcn_sched_barrier(0);
    __builtin_amdgcn_s_setprio(1);
    #pragma unroll
    for (int mf = 0; mf < 4; ++mf)
      #pragma unroll
      for (int nf = 0; nf < 2; ++nf) {
        acc[mf][2 + nf] = __builtin_amdgcn_mfma_f32_16x16x32_bf16(aF[mf][0], bF2[nf][0], acc[mf][2 + nf], 0, 0, 0);
        acc[mf][2 + nf] = __builtin_amdgcn_mfma_f32_16x16x32_bf16(aF[mf][1], bF2[nf][1], acc[mf][2 + nf], 0, 0, 0);
      }
    __builtin_amdgcn_s_setprio(0);
    asm volatile("s_waitcnt vmcnt(4)" ::: "memory");
    __builtin_amdgcn_s_barrier();
    // ---------------- Phase 3: Q(mf 4..7, nf 0..1) ----------------
    #pragma unroll
    for (int mf = 0; mf < 4; ++mf) { aF[mf][0] = rdA(buf, 4 + mf, 0); aF[mf][1] = rdA(buf, 4 + mf, 1); }
    stage(bufn, ktn, 2);
    __builtin_amdgcn_s_barrier();
    asm volatile("s_waitcnt lgkmcnt(0)" ::: "memory");
    __builtin_amdgcn_sched_barrier(0);
    __builtin_amdgcn_s_setprio(1);
    #pragma unroll
    for (int mf = 0; mf < 4; ++mf)
      #pragma unroll
      for (int nf = 0; nf < 2; ++nf) {
        acc[4 + mf][nf] = __builtin_amdgcn_mfma_f32_16x16x32_bf16(aF[mf][0], bF[nf][0], acc[4 + mf][nf], 0, 0, 0);
        acc[4 + mf][nf] = __builtin_amdgcn_mfma_f32_16x16x32_bf16(aF[mf][1], bF[nf][1], acc[4 + mf][nf], 0, 0, 0);
      }
    __builtin_amdgcn_s_setprio(0);
    __builtin_amdgcn_s_barrier();
    // ---------------- Phase 4: Q(mf 4..7, nf 2..3) ----------------
    stage(bufn, ktn, 3);
    __builtin_amdgcn_s_barrier();
    __builtin_amdgcn_s_setprio(1);
    #pragma unroll
    for (int mf = 0; mf < 4; ++mf)
      #pragma unroll
      for (int nf = 0; nf < 2; ++nf) {
        acc[4 + mf][2 + nf] = __builtin_amdgcn_mfma_f32_16x16x32_bf16(aF[mf][0], bF2[nf][0], acc[4 + mf][2 + nf], 0, 0, 0);
        acc[4 + mf][2 + nf] = __builtin_amdgcn_mfma_f32_16x16x32_bf16(aF[mf][1], bF2[nf][1], acc[4 + mf][2 + nf], 0, 0, 0);
      }
    __builtin_amdgcn_s_setprio(0);
    asm volatile("s_waitcnt vmcnt(4)" ::: "memory");
    __builtin_amdgcn_s_barrier();
    cur ^= 1;
  }
  asm volatile("s_waitcnt vmcnt(0)" ::: "memory");

  // epilogue: v = m0 + wm2*128 + mf*16 + l4*4 + r ; n = n0 + wn4*64 + nf*16 + rr
  const int vbase = m0 + wm2 * 128;
  const int nbase = n0 + wn4 * 64;
  #pragma unroll
  for (int mf = 0; mf < 8; ++mf) {
    #pragma unroll
    for (int r = 0; r < 4; ++r) {
      int v = vbase + mf * 16 + l4 * 4 + r;
      if (v < VV) {
        float bv = bias[v];
        #pragma unroll
        for (int nf = 0; nf < 4; ++nf) {
          int n = nbase + nf * 16 + rr;
          int bb = n / TT, tq = n - bb * TT;
          out[(size_t)bb * ((size_t)VV * TT) + (size_t)v * TT + tq] = acc[mf][nf][r] + bv;
        }
      }
    }
  }
}

// ---------------- fused persistent LSTM (all 24 steps, flag barrier) ----------------
__global__ __launch_bounds__(512, 1) void lstm_seq_k(
    const ushort_t* __restrict__ Whh,    // [4096][1024] bf16
    const float* __restrict__ xgT,       // [24][4096][128] f32, bias included
    ushort_t* __restrict__ hs,           // [3072][1024] bf16, row = b*24+t
    int* __restrict__ bar)
{
  __shared__ f32x4 red[6][64][4];        // 24 KB
  const int tid = threadIdx.x, wid = tid >> 6, lane = tid & 63;
  const int l16 = lane & 15, l4 = lane >> 4;
  const int bid = blockIdx.x;
  const int jblk = bid & 63, mblk = bid >> 6;
  const int j0 = jblk * 16, m0 = mblk * 32;
  const int ks = wid >> 1;
  const int msub = (wid & 1) * 16;
  int* flags = bar;
  int* rel = bar + 256;

  bf16x8 Breg[4][8];
  #pragma unroll
  for (int g = 0; g < 4; ++g) {
    const ushort_t* bp = Whh + ((size_t)(g * 1024 + j0 + l16) << 10) + ks * 256 + l4 * 8;
    #pragma unroll
    for (int kc = 0; kc < 8; ++kc)
      Breg[g][kc] = *reinterpret_cast<const bf16x8*>(bp + kc * 32);
  }
  const int arow = m0 + msub + l16;
  float c_reg[4] = {0.f, 0.f, 0.f, 0.f};

  for (int t = 0; t < TT; ++t) {
    f32x4 acc[4] = {};
    f32x4 xv[4];
    if (ks == 0) {
      const float* xp = xgT + ((size_t)(t * GG + j0 + l16)) * BB + m0 + msub + l4 * 4;
      #pragma unroll
      for (int g = 0; g < 4; ++g)
        xv[g] = *reinterpret_cast<const f32x4*>(xp + (size_t)g * 1024 * BB);
    }
    if (t > 0) {
      const u64* Ab = reinterpret_cast<const u64*>(
          hs + (((size_t)arow * TT + (t - 1)) << 10) + ks * 256 + l4 * 8);
      bf16x8 afs[8];
      #pragma unroll
      for (int kc = 0; kc < 8; ++kc) {
        union { u64 q[2]; bf16x8 v; } u;
        u.q[0] = __hip_atomic_load(Ab + kc * 8,     __ATOMIC_RELAXED, __HIP_MEMORY_SCOPE_AGENT);
        u.q[1] = __hip_atomic_load(Ab + kc * 8 + 1, __ATOMIC_RELAXED, __HIP_MEMORY_SCOPE_AGENT);
        afs[kc] = u.v;
      }
      #pragma unroll
      for (int kc = 0; kc < 8; ++kc)
        #pragma unroll
        for (int g = 0; g < 4; ++g)
          acc[g] = __builtin_amdgcn_mfma_f32_16x16x32_bf16(afs[kc], Breg[g][kc], acc[g], 0, 0, 0);
    }
    if (ks != 0) {
      int slot = (ks - 1) * 2 + (wid & 1);
      #pragma unroll
      for (int g = 0; g < 4; ++g) red[slot][lane][g] = acc[g];
    }
    __syncthreads();
    if (ks == 0) {
      #pragma unroll
      for (int s = 0; s < 3; ++s)
        #pragma unroll
        for (int g = 0; g < 4; ++g)
          acc[g] += red[s * 2 + (wid & 1)][lane][g];
      #pragma unroll
      for (int r = 0; r < 4; ++r) {
        int b = m0 + msub + l4 * 4 + r;
        float gi = acc[0][r] + xv[0][r];
        float gf = acc[1][r] + xv[1][r];
        float gg = acc[2][r] + xv[2][r];
        float go = acc[3][r] + xv[3][r];
        gi = 1.f / (1.f + expf(-gi));
        gf = 1.f / (1.f + expf(-gf));
        go = 1.f / (1.f + expf(-go));
        float cn = gf * c_reg[r] + gi * tanhf(gg);
        c_reg[r] = cn;
        float hn = go * tanhf(cn);
        unsigned hv = (unsigned)f2bf(hn);
        unsigned pv = (unsigned)__shfl_xor((int)hv, 1);
        if (!(l16 & 1)) {
          unsigned pk = (hv & 0xffffu) | (pv << 16);
          __hip_atomic_store(
              reinterpret_cast<unsigned*>(hs + (((size_t)b * TT + t) << 10) + j0 + l16),
              pk, __ATOMIC_RELAXED, __HIP_MEMORY_SCOPE_AGENT);
        }
      }
    }
    if (t < TT - 1) {
      __syncthreads();
      if (bid == 0) {
        if (wid == 0) {
          if (lane == 0)
            __hip_atomic_store(&flags[0], t + 1, __ATOMIC_RELAXED, __HIP_MEMORY_SCOPE_AGENT);
          for (;;) {
            int a0 = __hip_atomic_load(&flags[lane],       __ATOMIC_RELAXED, __HIP_MEMORY_SCOPE_AGENT);
            int a1 = __hip_atomic_load(&flags[lane +  64], __ATOMIC_RELAXED, __HIP_MEMORY_SCOPE_AGENT);
            int a2 = __hip_atomic_load(&flags[lane + 128], __ATOMIC_RELAXED, __HIP_MEMORY_SCOPE_AGENT);
            int a3 = __hip_atomic_load(&flags[lane + 192], __ATOMIC_RELAXED, __HIP_MEMORY_SCOPE_AGENT);
            int mn = min(min(a0, a1), min(a2, a3));
            if (__all(mn >= t + 1)) break;
            __builtin_amdgcn_s_sleep(2);
          }
          if (lane < 8)
            __hip_atomic_store(&rel[lane * 64], t + 1, __ATOMIC_RELAXED, __HIP_MEMORY_SCOPE_AGENT);
        }
      } else {
        if (tid == 0) {
          __hip_atomic_store(&flags[bid], t + 1, __ATOMIC_RELAXED, __HIP_MEMORY_SCOPE_AGENT);
          while (__hip_atomic_load(&rel[(bid & 7) * 64], __ATOMIC_RELAXED, __HIP_MEMORY_SCOPE_AGENT) < t + 1)
            __builtin_amdgcn_s_sleep(4);
        }
      }
      __syncthreads();
    }
  }
}

// ---------------- launcher ----------------

extern "C" void kernel_launch(void* const* d_in, const int* in_sizes, int n_in,
                              void* d_out, int out_size, void* d_ws, size_t ws_size,
                              hipStream_t stream) {
  const float* features = (const float*)d_in[0];
  const int*   captions = (const int*)d_in[1];
  const int*   pad_idx  = (const int*)d_in[2];
  const float* emb      = (const float*)d_in[3];
  const float* W_ih     = (const float*)d_in[4];
  const float* W_hh     = (const float*)d_in[5];
  const float* b_ih     = (const float*)d_in[6];
  const float* b_hh     = (const float*)d_in[7];
  const float* W_out    = (const float*)d_in[8];
  const float* b_out    = (const float*)d_in[9];
  float* out = (float*)d_out;

  char* w = (char*)d_ws;
  auto carve = [&](size_t bytes) {
    char* p = w;
    w += (bytes + 255) & ~(size_t)255;
    return p;
  };
  ushort_t* Wih_b  = (ushort_t*)carve((size_t)GG * HH * 2);
  ushort_t* Whh_b  = (ushort_t*)carve((size_t)GG * HH * 2);
  ushort_t* Wout_b = (ushort_t*)carve((size_t)MPAD * HH * 2);
  ushort_t* xa     = (ushort_t*)carve((size_t)MM * HH * 2);
  float*    xgT    = (float*)carve((size_t)MM * GG * 4);        // [24][4096][128]
  ushort_t* hs     = (ushort_t*)carve((size_t)MM * HH * 2);
  float*    bsum   = (float*)carve((size_t)GG * 4);
  int*      bar    = (int*)carve(4096);

  cast_bf16_k<<<dim3(1024), 256, 0, stream>>>(W_ih, Wih_b, GG * HH / 4);
  cast_bf16_k<<<dim3(1024), 256, 0, stream>>>(W_hh, Whh_b, GG * HH / 4);
  cast_bf16_k<<<dim3(2048), 256, 0, stream>>>(W_out, Wout_b, VV * HH / 4);
  bias_sum_k<<<dim3(16), 256, 0, stream>>>(b_ih, b_hh, bsum);
  build_xa_k<<<dim3(MM), 256, 0, stream>>>(emb, captions, pad_idx, features, xa);
  zero_bar_k<<<dim3(1), 256, 0, stream>>>(bar);

  // xgT: grid 768 = 8 XCDs x (12 m x 8 n)
  gemm_xg<<<dim3(768), 256, 0, stream>>>(xa, Wih_b, bsum, xgT, MM, GG, 8, 4);

  // all 24 LSTM steps in one persistent kernel
  lstm_seq_k<<<dim3(256), 512, 0, stream>>>(Whh_b, xgT, hs, bar);

  // logits: 118 x 12 tiles of 256 = 1416 = 8 x 177
  gemm256_logits<<<dim3(1416), 512, 0, stream>>>(Wout_b, hs, b_out, out);
}